// Round 19
// baseline (5474.649 us; speedup 1.0000x reference)
//
#include <hip/hip_runtime.h>

// ---------------------------------------------------------------------------
// Seq2SeqAttentionDecoder — round 19: 4-batch merged blocks
//  R18 analysis: gate phases are per-CU L2-BW bound (4 co-CU blocks with the
//  SAME sl each read the same 384KB weight slice -> 1.5MB/CU/phase at
//  ~135GB/s/CU ~= 11us). Fix: merge them -> 256 blocks x 1024 threads
//  (1/CU, same 16 waves). Block (bg,sl) handles b = bg*4+lb, lb = t>>8
//  (high bits => single-lb waves: LDS broadcast preserved, weight addresses
//  identical across lb-waves -> L1 dedup, per-CU weight traffic 4x down).
//  keys/enc: plain L2 loads (slices resident; 1 line/s-row fully used).
//  5 barriers/step over 32-block groups (8 groups). Math identical to R18.
// ---------------------------------------------------------------------------

#define BB 32
#define TT 64
#define SS 128
#define HH 1024
#define EE 512
#define VV 32000
#define H3 3072
#define NEGV (-1000000.0f)
#define NB 256          // persistent grid blocks (1/CU)
#define NT 1024

typedef __attribute__((ext_vector_type(8))) unsigned short u16x8;
typedef __attribute__((ext_vector_type(4))) unsigned short u16x4;
typedef __attribute__((ext_vector_type(8))) short s16x8;
typedef __attribute__((ext_vector_type(4))) float f32x4;

__device__ __forceinline__ unsigned short f2bf(float f) {
  unsigned int u = __builtin_bit_cast(unsigned int, f);
  unsigned int r = (u + 0x7FFFu + ((u >> 16) & 1u)) >> 16;   // RNE
  return (unsigned short)r;
}
__device__ __forceinline__ float bfu(unsigned short u) {
  return __builtin_bit_cast(float, (unsigned int)u << 16);
}
__device__ __forceinline__ float sigm(float x) {
  return 1.f / (1.f + __expf(-x));
}
__device__ __forceinline__ float tanhfast(float x) {
  float ax = fabsf(x);
  float e = __expf(2.f * ax);
  float th = 1.f - 2.f / (e + 1.f);
  return copysignf(th, x);
}

// ---- 2-way bf16 dot product ----
#if defined(__has_builtin)
#if __has_builtin(__builtin_amdgcn_fdot2_f32_bf16)
#define HAVE_DOT2BF 1
#endif
#endif
#ifdef HAVE_DOT2BF
typedef __attribute__((ext_vector_type(2))) __bf16 bf16x2;
__device__ __forceinline__ float dot2bf(unsigned w, unsigned x, float c) {
  return __builtin_amdgcn_fdot2_f32_bf16(__builtin_bit_cast(bf16x2, w),
                                         __builtin_bit_cast(bf16x2, x), c,
                                         false);
}
#else
__device__ __forceinline__ float dot2bf(unsigned w, unsigned x, float c) {
  c = fmaf(bfu((unsigned short)(w & 0xffffu)),
           bfu((unsigned short)(x & 0xffffu)), c);
  c = fmaf(bfu((unsigned short)(w >> 16)), bfu((unsigned short)(x >> 16)), c);
  return c;
}
#endif
__device__ __forceinline__ void dot8(float& acc, uint4 w, uint4 x) {
  acc = dot2bf(w.x, x.x, acc); acc = dot2bf(w.y, x.y, acc);
  acc = dot2bf(w.z, x.z, acc); acc = dot2bf(w.w, x.w, acc);
}

// L3-coherent state access (agent-scope relaxed atomics) — no fences
__device__ __forceinline__ float ldu(const float* p) {
  return __hip_atomic_load((float*)p, __ATOMIC_RELAXED, __HIP_MEMORY_SCOPE_AGENT);
}
__device__ __forceinline__ void stu(float* p, float v) {
  __hip_atomic_store(p, v, __ATOMIC_RELAXED, __HIP_MEMORY_SCOPE_AGENT);
}
__device__ __forceinline__ unsigned long long ldu64(const unsigned short* p) {
  return __hip_atomic_load((const unsigned long long*)p, __ATOMIC_RELAXED,
                           __HIP_MEMORY_SCOPE_AGENT);
}
__device__ __forceinline__ void stu16(unsigned short* p, unsigned short v) {
  __hip_atomic_store(p, v, __ATOMIC_RELAXED, __HIP_MEMORY_SCOPE_AGENT);
}

// ---------- init: h0A/h1i = bf16(hidden), zero barrier region ----------
// bar (u32): [0..4096) arrival flags (256 x 16); [4096..4224) 8 release lines.
__global__ __launch_bounds__(256) void k_init(const float* __restrict__ hid,
                                              unsigned short* __restrict__ h0A,
                                              unsigned short* __restrict__ h1i,
                                              unsigned* __restrict__ bar) {
  int i = blockIdx.x * 256 + threadIdx.x;
  if (i < BB * HH) h0A[i] = f2bf(hid[i]);
  else if (i < 2 * BB * HH) h1i[i - BB * HH] = f2bf(hid[i]);
  else if (i < 2 * BB * HH + 4224) bar[i - 2 * BB * HH] = 0u;
}

// ---------- gather xs[r=t*B+b][e] = bf16(emb[X[b][t]][e]) ----------
__global__ __launch_bounds__(256) void k_gather(const int* __restrict__ X,
                                                const float* __restrict__ emb,
                                                unsigned short* __restrict__ xs) {
  int idx = blockIdx.x * 256 + threadIdx.x;
  int r = idx >> 7, c4 = (idx & 127) << 2;
  int td = r >> 5, b = r & 31;
  int tok = X[b * TT + td];
  float4 v = *(const float4*)(emb + (size_t)tok * EE + c4);
  ushort4 o;
  o.x = f2bf(v.x); o.y = f2bf(v.y); o.z = f2bf(v.z); o.w = f2bf(v.w);
  *(ushort4*)(xs + (size_t)r * EE + c4) = o;
}

// ---------- fp32 -> packed bf16 (grid = rows) ----------
__global__ __launch_bounds__(256) void k_conv(const float* __restrict__ src,
                                              unsigned short* __restrict__ dst,
                                              int cols4, int ld) {
  int r = blockIdx.x;
  for (int c = threadIdx.x; c < cols4; c += 256) {
    float4 v = *(const float4*)(src + (size_t)r * ld + (size_t)c * 4);
    ushort4 o;
    o.x = f2bf(v.x); o.y = f2bf(v.y); o.z = f2bf(v.z); o.w = f2bf(v.w);
    *(ushort4*)(dst + (size_t)r * cols4 * 4 + (size_t)c * 4) = o;
  }
}

// ---------- bf16 MFMA GEMM (m97 structure): C[M,N] = A@W^T (+bias) ----------
__global__ __launch_bounds__(256) void k_gemm_mfma(
    const unsigned short* __restrict__ A, const unsigned short* __restrict__ W,
    const float* __restrict__ bias, float* __restrict__ C,
    int M, int N, int K, int permuteBT, int outBF16) {
  __shared__ unsigned short As[128 * 32];
  __shared__ unsigned short Bs[128 * 32];
  const int m0 = blockIdx.y * 128, n0 = blockIdx.x * 128;
  const int t = threadIdx.x;
  const int lane = t & 63, w = t >> 6;
  const int wr = w >> 1, wc = w & 1;
  const int fr = lane & 15, fq = lane >> 4;
  const int srow = t >> 2;
  const int scol = (t & 3) * 8;
  f32x4 acc[4][4] = {};
  for (int k0 = 0; k0 < K; k0 += 32) {
#pragma unroll
    for (int i = 0; i < 2; ++i) {
      __builtin_amdgcn_global_load_lds(
          (const __attribute__((address_space(1))) void*)(A + (size_t)(m0 + i * 64 + srow) * K + k0 + scol),
          (__attribute__((address_space(3))) void*)((char*)As + i * 4096 + w * 1024),
          16, 0, 0);
      __builtin_amdgcn_global_load_lds(
          (const __attribute__((address_space(1))) void*)(W + (size_t)(n0 + i * 64 + srow) * K + k0 + scol),
          (__attribute__((address_space(3))) void*)((char*)Bs + i * 4096 + w * 1024),
          16, 0, 0);
    }
    __syncthreads();
    s16x8 af[4], bf[4];
#pragma unroll
    for (int mi = 0; mi < 4; ++mi)
      af[mi] = *(const s16x8*)(As + (wr * 64 + mi * 16 + fr) * 32 + fq * 8);
#pragma unroll
    for (int ni = 0; ni < 4; ++ni)
      bf[ni] = *(const s16x8*)(Bs + (wc * 64 + ni * 16 + fr) * 32 + fq * 8);
#pragma unroll
    for (int mi = 0; mi < 4; ++mi)
#pragma unroll
      for (int ni = 0; ni < 4; ++ni)
        acc[mi][ni] = __builtin_amdgcn_mfma_f32_16x16x32_bf16(
            af[mi], bf[ni], acc[mi][ni], 0, 0, 0);
    __syncthreads();
  }
#pragma unroll
  for (int mi = 0; mi < 4; ++mi) {
#pragma unroll
    for (int ni = 0; ni < 4; ++ni) {
      int gc = n0 + wc * 64 + ni * 16 + fr;
      float bv = bias ? bias[gc] : 0.f;
#pragma unroll
      for (int j = 0; j < 4; ++j) {
        int gm = m0 + wr * 64 + mi * 16 + fq * 4 + j;
        size_t ro = permuteBT ? ((size_t)((gm & 31) * TT + (gm >> 5))) * N
                              : (size_t)gm * N;
        float v = acc[mi][ni][j] + bv;
        if (outBF16) ((unsigned short*)C)[ro + gc] = f2bf(v);
        else         C[ro + gc] = v;
      }
    }
  }
}

// ---------- gates + GRU (per-lb quarter); x staged, y pre-staged ----------
__device__ __forceinline__ void gru_phase(
    int sl, int lb, int tl, unsigned* sxu, const unsigned* syu,
    const unsigned short* __restrict__ xg,
    const unsigned short* __restrict__ wi, const unsigned short* __restrict__ wh,
    const unsigned short* __restrict__ gixrow, const float* __restrict__ bih,
    const float* __restrict__ bhh, unsigned short* __restrict__ hdst) {
  {
    unsigned long long vx = ldu64(xg + tl * 4);
    sxu[tl * 2] = (unsigned)vx; sxu[tl * 2 + 1] = (unsigned)(vx >> 32);
  }
  __syncthreads();
  const int nl = tl >> 3, q8 = tl & 7;    // 32 n x 8 k-groups per lb
  const int n = sl * 32 + nl;
  const unsigned short* wr = wi + (size_t)n * HH + q8 * 8;
  const unsigned short* hr = wh + (size_t)n * HH + q8 * 8;
  float air = 0, aiz = 0, ain = 0, ahr = 0, ahz = 0, ahn = 0;
#pragma unroll 2
  for (int j = 0; j < 16; ++j) {
    const int ku = q8 * 4 + j * 32;
    uint4 xv = *(const uint4*)(sxu + ku);
    uint4 yv = *(const uint4*)(syu + ku);
    const unsigned short* wj = wr + j * 64;
    const unsigned short* hj = hr + j * 64;
    dot8(air, *(const uint4*)(wj),           xv);
    dot8(aiz, *(const uint4*)(wj + 1048576), xv);
    dot8(ain, *(const uint4*)(wj + 2097152), xv);
    dot8(ahr, *(const uint4*)(hj),           yv);
    dot8(ahz, *(const uint4*)(hj + 1048576), yv);
    dot8(ahn, *(const uint4*)(hj + 2097152), yv);
  }
  air += __shfl_xor(air, 1); air += __shfl_xor(air, 2); air += __shfl_xor(air, 4);
  aiz += __shfl_xor(aiz, 1); aiz += __shfl_xor(aiz, 2); aiz += __shfl_xor(aiz, 4);
  ain += __shfl_xor(ain, 1); ain += __shfl_xor(ain, 2); ain += __shfl_xor(ain, 4);
  ahr += __shfl_xor(ahr, 1); ahr += __shfl_xor(ahr, 2); ahr += __shfl_xor(ahr, 4);
  ahz += __shfl_xor(ahz, 1); ahz += __shfl_xor(ahz, 2); ahz += __shfl_xor(ahz, 4);
  ahn += __shfl_xor(ahn, 1); ahn += __shfl_xor(ahn, 2); ahn += __shfl_xor(ahn, 4);
  if (q8 == 0) {
    float gr = air, gz = aiz, gn = ain;
    if (gixrow) {
      gr += bfu(__builtin_nontemporal_load(gixrow + n));
      gz += bfu(__builtin_nontemporal_load(gixrow + HH + n));
      gn += bfu(__builtin_nontemporal_load(gixrow + 2 * HH + n));
    }
    if (bih) { gr += bih[n]; gz += bih[HH + n]; gn += bih[2 * HH + n]; }
    float h_r = ahr + bhh[n], h_z = ahz + bhh[HH + n], h_n = ahn + bhh[2 * HH + n];
    float r = sigm(gr + h_r);
    float z = sigm(gz + h_z);
    float nn = tanhfast(gn + r * h_n);
    unsigned yw = syu[n >> 1];
    float hp = bfu((unsigned short)((n & 1) ? (yw >> 16) : (yw & 0xffffu)));
    stu16(hdst + n, f2bf((1.f - z) * nn + z * hp));
  }
}

// ---------- the persistent recurrence kernel (256 x 1024) ----------
__global__ __launch_bounds__(1024, 1) void k_persist(
    const unsigned short* __restrict__ keysb,
    const unsigned short* __restrict__ encb,
    const unsigned short* __restrict__ gi0xb,
    const unsigned short* __restrict__ wqb,
    const unsigned short* __restrict__ wi0, const unsigned short* __restrict__ wh0,
    const unsigned short* __restrict__ wi1, const unsigned short* __restrict__ wh1,
    const float* __restrict__ wv, const int* __restrict__ vlen,
    const unsigned short* __restrict__ h1i,
    const float* __restrict__ bhh0, const float* __restrict__ bih1,
    const float* __restrict__ bhh1,
    float* __restrict__ partial, float* __restrict__ scores,
    unsigned short* __restrict__ ctxb,
    unsigned short* __restrict__ h0A, unsigned short* __restrict__ h0B,
    unsigned short* __restrict__ outsb,
    unsigned* __restrict__ bar) {
  __shared__ unsigned sh1u[4][512];   // h1old rows (P12 q, P5 y)
  __shared__ unsigned sh0u[4][512];   // h0old rows (P4 y)
  __shared__ unsigned sxu[4][512];    // x-side (ctx / h0new)
  __shared__ float qs[4][32];
  __shared__ float aux[4][640];
  const int bid = blockIdx.x, t = threadIdx.x;
  const int bg = bid >> 5, sl = bid & 31;
  const int lb = t >> 8, tl = t & 255;
  const int b = bg * 4 + lb;
  const int vb = vlen[b];
  unsigned* rel = bar + 4096;         // 8 group release lines x 16 u32
  unsigned ep = 0;

  // 32-block group barrier (group = bg): flag arrive, sl==0 collects.
#define GBAR() do { ++ep; __syncthreads();                                     \
    if (t == 0)                                                                \
      __hip_atomic_store(bar + bid * 16, ep, __ATOMIC_RELAXED,                 \
                         __HIP_MEMORY_SCOPE_AGENT);                            \
    if (sl == 0) {                                                             \
      if (t < 32)                                                              \
        while (__hip_atomic_load(bar + (bg * 32 + t) * 16, __ATOMIC_RELAXED,   \
                                 __HIP_MEMORY_SCOPE_AGENT) < ep)               \
          __builtin_amdgcn_s_sleep(1);                                         \
      __syncthreads();                                                         \
      if (t == 0)                                                              \
        __hip_atomic_store(rel + bg * 16, ep, __ATOMIC_RELAXED,                \
                           __HIP_MEMORY_SCOPE_AGENT);                          \
    } else if (t == 0) {                                                       \
      while (__hip_atomic_load(rel + bg * 16, __ATOMIC_RELAXED,                \
                               __HIP_MEMORY_SCOPE_AGENT) < ep)                 \
        __builtin_amdgcn_s_sleep(1);                                           \
    }                                                                          \
    __syncthreads(); } while (0)

  for (int td = 0; td < TT; ++td) {
    const unsigned short* h1old =
        td ? outsb + (size_t)(td - 1) * BB * HH : h1i;
    const unsigned short* h0old = (td & 1) ? h0B : h0A;
    unsigned short*       h0new = (td & 1) ? h0A : h0B;

    // ---- P12: stage h1+h0 (4 b), q slice (dot2), partial scores ----
    {
      {
        unsigned long long v1 = ldu64(h1old + (size_t)b * HH + tl * 4);
        unsigned long long v0 = ldu64(h0old + (size_t)b * HH + tl * 4);
        sh1u[lb][tl * 2] = (unsigned)v1;
        sh1u[lb][tl * 2 + 1] = (unsigned)(v1 >> 32);
        sh0u[lb][tl * 2] = (unsigned)v0;
        sh0u[lb][tl * 2 + 1] = (unsigned)(v0 >> 32);
      }
      __syncthreads();
      {
        const int nl = tl >> 3, q8 = tl & 7;
        const unsigned short* wr = wqb + (size_t)(sl * 32 + nl) * HH + q8 * 8;
        float acc = 0;
#pragma unroll 4
        for (int j = 0; j < 16; ++j) {
          const int ku = q8 * 4 + j * 32;
          uint4 xv = *(const uint4*)(&sh1u[lb][ku]);
          dot8(acc, *(const uint4*)(wr + j * 64), xv);
        }
        acc += __shfl_xor(acc, 1); acc += __shfl_xor(acc, 2);
        acc += __shfl_xor(acc, 4);
        if (q8 == 0) qs[lb][nl] = acc;
      }
      __syncthreads();
      const int s = tl >> 1, hf = tl & 1;
      if (s < vb) {
        const unsigned short* kr =
            keysb + (size_t)(b * SS + s) * HH + sl * 32 + hf * 16;
        const float* wvp = wv + sl * 32 + hf * 16;
        const float* qp = &qs[lb][hf * 16];
        float a = 0;
#pragma unroll
        for (int j = 0; j < 4; ++j) {
          u16x4 kv = *(const u16x4*)(kr + j * 4);
          float4 wvv = *(const float4*)(wvp + j * 4);
          a = fmaf(tanhfast(qp[j * 4 + 0] + bfu(kv[0])), wvv.x, a);
          a = fmaf(tanhfast(qp[j * 4 + 1] + bfu(kv[1])), wvv.y, a);
          a = fmaf(tanhfast(qp[j * 4 + 2] + bfu(kv[2])), wvv.z, a);
          a = fmaf(tanhfast(qp[j * 4 + 3] + bfu(kv[3])), wvv.w, a);
        }
        a += __shfl_xor(a, 1);
        if (hf == 0) stu(partial + ((size_t)(b * SS + s)) * 32 + sl, a);
      }
    }
    GBAR();

    // ---- P3a: sum this block's 4 s-rows per lb (32 partials each) ----
    if (tl < 128) {
      const int s = sl * 4 + (tl >> 5), g = tl & 31;
      float a = 0;
      if (s < vb) {
        a = ldu(partial + ((size_t)(b * SS + s)) * 32 + g);
        a += __shfl_xor(a, 1); a += __shfl_xor(a, 2); a += __shfl_xor(a, 4);
        a += __shfl_xor(a, 8); a += __shfl_xor(a, 16);
      }
      if (g == 0) stu(scores + b * SS + s, (s < vb) ? a : NEGV);
    }
    GBAR();

    // ---- P3b: softmax -> ctx slice (enc via L2) ----
    {
      if (tl < SS) aux[lb][tl] = ldu(scores + b * SS + tl);
      __syncthreads();
      float mx = aux[lb][0];
      for (int s = 1; s < vb; ++s) mx = fmaxf(mx, aux[lb][s]);
      float p = (tl < SS) ? __expf(aux[lb][tl] - mx) : 0.f;
      __syncthreads();
      if (tl < SS) aux[lb][tl] = p;
      __syncthreads();
      float sum = 0;
      for (int s = 0; s < vb; ++s) sum += aux[lb][s];
      const float inv = 1.f / sum;
      const int cp = tl & 15, sg = tl >> 4;
      float a0 = 0, a1 = 0;
      const int send = min((sg + 1) * 8, vb);
      for (int s = sg * 8; s < send; ++s) {
        unsigned e2 = *(const unsigned*)(
            encb + (size_t)(b * SS + s) * HH + sl * 32 + cp * 2);
        float pp = aux[lb][s];
        a0 = fmaf(pp, bfu((unsigned short)(e2 & 0xffffu)), a0);
        a1 = fmaf(pp, bfu((unsigned short)(e2 >> 16)), a1);
      }
      __syncthreads();
      aux[lb][SS + sg * 32 + cp * 2]     = a0;
      aux[lb][SS + sg * 32 + cp * 2 + 1] = a1;
      __syncthreads();
      if (tl < 32) {
        float v = 0;
#pragma unroll
        for (int g2 = 0; g2 < 16; ++g2) v += aux[lb][SS + g2 * 32 + tl];
        stu16(ctxb + (size_t)b * HH + sl * 32 + tl, f2bf(v * inv));
      }
    }
    GBAR();

    // ---- P4: layer-0 gates + GRU -> h0new (y = pre-staged h0old) ----
    gru_phase(sl, lb, tl, sxu[lb], sh0u[lb], ctxb + (size_t)b * HH, wi0, wh0,
              gi0xb + ((size_t)td * BB + b) * H3, nullptr, bhh0,
              h0new + (size_t)b * HH);
    GBAR();

    // ---- P5: layer-1 gates + GRU -> outsb[td] (y = reused h1old LDS) ----
    gru_phase(sl, lb, tl, sxu[lb], sh1u[lb], h0new + (size_t)b * HH, wi1, wh1,
              nullptr, bih1, bhh1,
              outsb + (size_t)td * BB * HH + (size_t)b * HH);
    GBAR();
  }
#undef GBAR
}

// ---------------------------------------------------------------------------
extern "C" void kernel_launch(void* const* d_in, const int* in_sizes, int n_in,
                              void* d_out, int out_size, void* d_ws,
                              size_t ws_size, hipStream_t stream) {
  const int*   X    = (const int*)  d_in[0];
  const float* enc  = (const float*)d_in[1];
  const float* hid  = (const float*)d_in[2];
  const int*   vlen = (const int*)  d_in[3];
  const float* emb  = (const float*)d_in[4];
  const float* Wq   = (const float*)d_in[5];
  const float* Wk   = (const float*)d_in[6];
  const float* wv   = (const float*)d_in[7];
  const float* Wih0 = (const float*)d_in[8];
  const float* Whh0 = (const float*)d_in[9];
  const float* bih0 = (const float*)d_in[10];
  const float* bhh0 = (const float*)d_in[11];
  const float* Wih1 = (const float*)d_in[12];
  const float* Whh1 = (const float*)d_in[13];
  const float* bih1 = (const float*)d_in[14];
  const float* bhh1 = (const float*)d_in[15];
  const float* Wout = (const float*)d_in[16];
  const float* bout = (const float*)d_in[17];
  float* out = (float*)d_out;

  // ---- workspace (float offsets), ~70.6 MB ----
  float* ws = (float*)d_ws;
  unsigned short* wi0b   = (unsigned short*)ws;                 // 4 gate mats
  unsigned short* wh0b   = wi0b + (size_t)3145728;
  unsigned short* wi1b   = wh0b + (size_t)3145728;
  unsigned short* wh1b   = wi1b + (size_t)3145728;
  unsigned short* wqb    = (unsigned short*)(ws + 6291456);
  unsigned short* gi0xb  = (unsigned short*)(ws + 6815744);
  unsigned short* keysb  = (unsigned short*)(ws + 9961472);
  unsigned short* encb   = (unsigned short*)(ws + 12058624);
  unsigned short* xsb    = (unsigned short*)(ws + 14155776);    // prologue only
  unsigned short* wkb    = (unsigned short*)(ws + 14680064);    // prologue only
  unsigned short* wih0xb = (unsigned short*)(ws + 15204352);    // prologue only
  unsigned short* woutb  = (unsigned short*)ws;                 // overlay
  unsigned short* outsb  = (unsigned short*)(ws + 16384000);
  unsigned short* h0A    = (unsigned short*)(ws + 17432576);
  unsigned short* h0B    = (unsigned short*)(ws + 17448960);
  unsigned short* h1i    = (unsigned short*)(ws + 17465344);
  unsigned short* ctxb   = (unsigned short*)(ws + 17481728);
  float*          partial= ws + 17498112;                       // 131,072 f
  float*          scores = ws + 17629184;                       //   4,096 f
  unsigned*       bar    = (unsigned*)(ws + 17633280);          //  4,224 u32

  k_init<<<273, 256, 0, stream>>>(hid, h0A, h1i, bar);
  k_gather<<<1024, 256, 0, stream>>>(X, emb, xsb);
  // bf16 converts for prologue GEMMs
  k_conv<<<4096, 256, 0, stream>>>(enc, encb, 256, HH);
  k_conv<<<1024, 256, 0, stream>>>(Wk, wkb, 256, HH);
  k_conv<<<3072, 256, 0, stream>>>(Wih0 + HH, wih0xb, 128, HH + EE);
  // keysb = bf16(enc @ Wk^T)
  k_gemm_mfma<<<dim3(8, 32), 256, 0, stream>>>(encb, wkb, nullptr,
                                               (float*)keysb, BB * SS, HH, HH,
                                               0, 1);
  // gi0xb = bf16(xs @ W_ih0[:,H:]^T + b_ih0)
  k_gemm_mfma<<<dim3(24, 16), 256, 0, stream>>>(xsb, wih0xb, bih0,
                                                (float*)gi0xb, TT * BB, H3, EE,
                                                0, 1);
  // recurrent weights -> bf16
  k_conv<<<1024, 256, 0, stream>>>(Wq, wqb, 256, HH);
  k_conv<<<3072, 256, 0, stream>>>(Wih0, wi0b, 256, HH + EE);  // ctx cols only
  k_conv<<<3072, 256, 0, stream>>>(Whh0, wh0b, 256, HH);
  k_conv<<<3072, 256, 0, stream>>>(Wih1, wi1b, 256, HH);
  k_conv<<<3072, 256, 0, stream>>>(Whh1, wh1b, 256, HH);

  // the whole 64-step recurrence, one launch, 8 groups of 32 blocks
  k_persist<<<NB, NT, 0, stream>>>(keysb, encb, gi0xb, wqb,
                                   wi0b, wh0b, wi1b, wh1b,
                                   wv, vlen, h1i,
                                   bhh0, bih1, bhh1,
                                   partial, scores, ctxb, h0A, h0B, outsb, bar);

  // Wout -> bf16 into the now-dead overlay, then MFMA logits GEMM
  k_conv<<<32000, 256, 0, stream>>>(Wout, woutb, 256, HH);
  k_gemm_mfma<<<dim3(250, 16), 256, 0, stream>>>(outsb, woutb, bout, out,
                                                 TT * BB, VV, HH, 1, 0);
}

// Round 20
// 4435.257 us; speedup vs baseline: 1.2343x; 1.2343x over previous
//
#include <hip/hip_runtime.h>

// ---------------------------------------------------------------------------
// Seq2SeqAttentionDecoder — round 20: revert to R18 (best, 4404 us total)
//  R19 (merged 1024-thread blocks) regressed: lost keys/enc LDS staging
//  (FETCH 0.42->1.29 GB) and no L1 weight dedup materialized. R16/R17/R19
//  all traded a proven win for the weight-redundancy fix and lost.
//  This is R18 verbatim:
//   * persistent fence-free recurrence, 1024 blocks x 256 thr (4/CU)
//   * per-b 32-block group barriers (flag arrive + group release line)
//   * bf16 everything: weights, state (L3-coherent relaxed atomics), streams
//   * dot2 gates (v_dot2_f32_bf16), LDS-staged keys/enc slices (step-invariant)
//   * two-stage score reduce (P3a/P3b), h1/h0 LDS rows staged once per step
//   * MFMA bf16 prologue GEMMs + logits GEMM (m97 structure)
// ---------------------------------------------------------------------------

#define BB 32
#define TT 64
#define SS 128
#define HH 1024
#define EE 512
#define VV 32000
#define H3 3072
#define NEGV (-1000000.0f)
#define NB 1024         // persistent grid blocks (4/CU exact residency)

typedef __attribute__((ext_vector_type(8))) unsigned short u16x8;
typedef __attribute__((ext_vector_type(4))) unsigned short u16x4;
typedef __attribute__((ext_vector_type(8))) short s16x8;
typedef __attribute__((ext_vector_type(4))) float f32x4;

__device__ __forceinline__ unsigned short f2bf(float f) {
  unsigned int u = __builtin_bit_cast(unsigned int, f);
  unsigned int r = (u + 0x7FFFu + ((u >> 16) & 1u)) >> 16;   // RNE
  return (unsigned short)r;
}
__device__ __forceinline__ float bfu(unsigned short u) {
  return __builtin_bit_cast(float, (unsigned int)u << 16);
}
__device__ __forceinline__ float sigm(float x) {
  return 1.f / (1.f + __expf(-x));
}
__device__ __forceinline__ float tanhfast(float x) {
  float ax = fabsf(x);
  float e = __expf(2.f * ax);
  float th = 1.f - 2.f / (e + 1.f);
  return copysignf(th, x);
}

// ---- 2-way bf16 dot product ----
#if defined(__has_builtin)
#if __has_builtin(__builtin_amdgcn_fdot2_f32_bf16)
#define HAVE_DOT2BF 1
#endif
#endif
#ifdef HAVE_DOT2BF
typedef __attribute__((ext_vector_type(2))) __bf16 bf16x2;
__device__ __forceinline__ float dot2bf(unsigned w, unsigned x, float c) {
  return __builtin_amdgcn_fdot2_f32_bf16(__builtin_bit_cast(bf16x2, w),
                                         __builtin_bit_cast(bf16x2, x), c,
                                         false);
}
#else
__device__ __forceinline__ float dot2bf(unsigned w, unsigned x, float c) {
  c = fmaf(bfu((unsigned short)(w & 0xffffu)),
           bfu((unsigned short)(x & 0xffffu)), c);
  c = fmaf(bfu((unsigned short)(w >> 16)), bfu((unsigned short)(x >> 16)), c);
  return c;
}
#endif
__device__ __forceinline__ void dot8(float& acc, uint4 w, uint4 x) {
  acc = dot2bf(w.x, x.x, acc); acc = dot2bf(w.y, x.y, acc);
  acc = dot2bf(w.z, x.z, acc); acc = dot2bf(w.w, x.w, acc);
}

// L3-coherent state access (agent-scope relaxed atomics) — no fences
__device__ __forceinline__ float ldu(const float* p) {
  return __hip_atomic_load((float*)p, __ATOMIC_RELAXED, __HIP_MEMORY_SCOPE_AGENT);
}
__device__ __forceinline__ void stu(float* p, float v) {
  __hip_atomic_store(p, v, __ATOMIC_RELAXED, __HIP_MEMORY_SCOPE_AGENT);
}
__device__ __forceinline__ unsigned long long ldu64(const unsigned short* p) {
  return __hip_atomic_load((const unsigned long long*)p, __ATOMIC_RELAXED,
                           __HIP_MEMORY_SCOPE_AGENT);
}
__device__ __forceinline__ void stu16(unsigned short* p, unsigned short v) {
  __hip_atomic_store(p, v, __ATOMIC_RELAXED, __HIP_MEMORY_SCOPE_AGENT);
}

// ---------- init: h0A/h1i = bf16(hidden), zero barrier region ----------
// bar (u32): [0..16384) arrival flags (1024 x 16); [16384..16896) 32 group
// release lines x 16.
__global__ __launch_bounds__(256) void k_init(const float* __restrict__ hid,
                                              unsigned short* __restrict__ h0A,
                                              unsigned short* __restrict__ h1i,
                                              unsigned* __restrict__ bar) {
  int i = blockIdx.x * 256 + threadIdx.x;
  if (i < BB * HH) h0A[i] = f2bf(hid[i]);
  else if (i < 2 * BB * HH) h1i[i - BB * HH] = f2bf(hid[i]);
  else if (i < 2 * BB * HH + 16896) bar[i - 2 * BB * HH] = 0u;
}

// ---------- gather xs[r=t*B+b][e] = bf16(emb[X[b][t]][e]) ----------
__global__ __launch_bounds__(256) void k_gather(const int* __restrict__ X,
                                                const float* __restrict__ emb,
                                                unsigned short* __restrict__ xs) {
  int idx = blockIdx.x * 256 + threadIdx.x;
  int r = idx >> 7, c4 = (idx & 127) << 2;
  int td = r >> 5, b = r & 31;
  int tok = X[b * TT + td];
  float4 v = *(const float4*)(emb + (size_t)tok * EE + c4);
  ushort4 o;
  o.x = f2bf(v.x); o.y = f2bf(v.y); o.z = f2bf(v.z); o.w = f2bf(v.w);
  *(ushort4*)(xs + (size_t)r * EE + c4) = o;
}

// ---------- fp32 -> packed bf16 (grid = rows) ----------
__global__ __launch_bounds__(256) void k_conv(const float* __restrict__ src,
                                              unsigned short* __restrict__ dst,
                                              int cols4, int ld) {
  int r = blockIdx.x;
  for (int c = threadIdx.x; c < cols4; c += 256) {
    float4 v = *(const float4*)(src + (size_t)r * ld + (size_t)c * 4);
    ushort4 o;
    o.x = f2bf(v.x); o.y = f2bf(v.y); o.z = f2bf(v.z); o.w = f2bf(v.w);
    *(ushort4*)(dst + (size_t)r * cols4 * 4 + (size_t)c * 4) = o;
  }
}

// ---------- bf16 MFMA GEMM (m97 structure): C[M,N] = A@W^T (+bias) ----------
__global__ __launch_bounds__(256) void k_gemm_mfma(
    const unsigned short* __restrict__ A, const unsigned short* __restrict__ W,
    const float* __restrict__ bias, float* __restrict__ C,
    int M, int N, int K, int permuteBT, int outBF16) {
  __shared__ unsigned short As[128 * 32];
  __shared__ unsigned short Bs[128 * 32];
  const int m0 = blockIdx.y * 128, n0 = blockIdx.x * 128;
  const int t = threadIdx.x;
  const int lane = t & 63, w = t >> 6;
  const int wr = w >> 1, wc = w & 1;
  const int fr = lane & 15, fq = lane >> 4;
  const int srow = t >> 2;
  const int scol = (t & 3) * 8;
  f32x4 acc[4][4] = {};
  for (int k0 = 0; k0 < K; k0 += 32) {
#pragma unroll
    for (int i = 0; i < 2; ++i) {
      __builtin_amdgcn_global_load_lds(
          (const __attribute__((address_space(1))) void*)(A + (size_t)(m0 + i * 64 + srow) * K + k0 + scol),
          (__attribute__((address_space(3))) void*)((char*)As + i * 4096 + w * 1024),
          16, 0, 0);
      __builtin_amdgcn_global_load_lds(
          (const __attribute__((address_space(1))) void*)(W + (size_t)(n0 + i * 64 + srow) * K + k0 + scol),
          (__attribute__((address_space(3))) void*)((char*)Bs + i * 4096 + w * 1024),
          16, 0, 0);
    }
    __syncthreads();
    s16x8 af[4], bf[4];
#pragma unroll
    for (int mi = 0; mi < 4; ++mi)
      af[mi] = *(const s16x8*)(As + (wr * 64 + mi * 16 + fr) * 32 + fq * 8);
#pragma unroll
    for (int ni = 0; ni < 4; ++ni)
      bf[ni] = *(const s16x8*)(Bs + (wc * 64 + ni * 16 + fr) * 32 + fq * 8);
#pragma unroll
    for (int mi = 0; mi < 4; ++mi)
#pragma unroll
      for (int ni = 0; ni < 4; ++ni)
        acc[mi][ni] = __builtin_amdgcn_mfma_f32_16x16x32_bf16(
            af[mi], bf[ni], acc[mi][ni], 0, 0, 0);
    __syncthreads();
  }
#pragma unroll
  for (int mi = 0; mi < 4; ++mi) {
#pragma unroll
    for (int ni = 0; ni < 4; ++ni) {
      int gc = n0 + wc * 64 + ni * 16 + fr;
      float bv = bias ? bias[gc] : 0.f;
#pragma unroll
      for (int j = 0; j < 4; ++j) {
        int gm = m0 + wr * 64 + mi * 16 + fq * 4 + j;
        size_t ro = permuteBT ? ((size_t)((gm & 31) * TT + (gm >> 5))) * N
                              : (size_t)gm * N;
        float v = acc[mi][ni][j] + bv;
        if (outBF16) ((unsigned short*)C)[ro + gc] = f2bf(v);
        else         C[ro + gc] = v;
      }
    }
  }
}

// ---------- gates + GRU via dot2; 32-n slice, 8-thread k-split ----------
// Stages x into sxu; y is PRE-STAGED (syu). hprev read from syu.
__device__ __forceinline__ void gru_phase(
    int sl, int t, unsigned* sxu, const unsigned* syu,
    const unsigned short* __restrict__ xg,
    const unsigned short* __restrict__ wi, const unsigned short* __restrict__ wh,
    const unsigned short* __restrict__ gixrow, const float* __restrict__ bih,
    const float* __restrict__ bhh, unsigned short* __restrict__ hdst) {
  {
    unsigned long long vx = ldu64(xg + t * 4);
    sxu[t * 2] = (unsigned)vx; sxu[t * 2 + 1] = (unsigned)(vx >> 32);
  }
  __syncthreads();
  const int nl = t >> 3, q8 = t & 7;      // 32 n x 8 k-groups
  const int n = sl * 32 + nl;
  const unsigned short* wr = wi + (size_t)n * HH + q8 * 8;
  const unsigned short* hr = wh + (size_t)n * HH + q8 * 8;
  float air = 0, aiz = 0, ain = 0, ahr = 0, ahz = 0, ahn = 0;
#pragma unroll 2
  for (int j = 0; j < 16; ++j) {
    const int ku = q8 * 4 + j * 32;       // u32 index (8 bf16 = 4 u32)
    uint4 xv = *(const uint4*)(sxu + ku);
    uint4 yv = *(const uint4*)(syu + ku);
    const unsigned short* wj = wr + j * 64;
    const unsigned short* hj = hr + j * 64;
    dot8(air, *(const uint4*)(wj),           xv);
    dot8(aiz, *(const uint4*)(wj + 1048576), xv);
    dot8(ain, *(const uint4*)(wj + 2097152), xv);
    dot8(ahr, *(const uint4*)(hj),           yv);
    dot8(ahz, *(const uint4*)(hj + 1048576), yv);
    dot8(ahn, *(const uint4*)(hj + 2097152), yv);
  }
  air += __shfl_xor(air, 1); air += __shfl_xor(air, 2); air += __shfl_xor(air, 4);
  aiz += __shfl_xor(aiz, 1); aiz += __shfl_xor(aiz, 2); aiz += __shfl_xor(aiz, 4);
  ain += __shfl_xor(ain, 1); ain += __shfl_xor(ain, 2); ain += __shfl_xor(ain, 4);
  ahr += __shfl_xor(ahr, 1); ahr += __shfl_xor(ahr, 2); ahr += __shfl_xor(ahr, 4);
  ahz += __shfl_xor(ahz, 1); ahz += __shfl_xor(ahz, 2); ahz += __shfl_xor(ahz, 4);
  ahn += __shfl_xor(ahn, 1); ahn += __shfl_xor(ahn, 2); ahn += __shfl_xor(ahn, 4);
  if (q8 == 0) {
    float gr = air, gz = aiz, gn = ain;
    if (gixrow) {
      gr += bfu(__builtin_nontemporal_load(gixrow + n));
      gz += bfu(__builtin_nontemporal_load(gixrow + HH + n));
      gn += bfu(__builtin_nontemporal_load(gixrow + 2 * HH + n));
    }
    if (bih) { gr += bih[n]; gz += bih[HH + n]; gn += bih[2 * HH + n]; }
    float h_r = ahr + bhh[n], h_z = ahz + bhh[HH + n], h_n = ahn + bhh[2 * HH + n];
    float r = sigm(gr + h_r);
    float z = sigm(gz + h_z);
    float nn = tanhfast(gn + r * h_n);
    unsigned yw = syu[n >> 1];
    float hp = bfu((unsigned short)((n & 1) ? (yw >> 16) : (yw & 0xffffu)));
    stu16(hdst + n, f2bf((1.f - z) * nn + z * hp));
  }
}

// ---------- the persistent recurrence kernel (per-b 32-block groups) ----------
__global__ __launch_bounds__(256, 4) void k_persist(
    const unsigned short* __restrict__ keysb,
    const unsigned short* __restrict__ encb,
    const unsigned short* __restrict__ gi0xb,
    const unsigned short* __restrict__ wqb,
    const unsigned short* __restrict__ wi0, const unsigned short* __restrict__ wh0,
    const unsigned short* __restrict__ wi1, const unsigned short* __restrict__ wh1,
    const float* __restrict__ wv, const int* __restrict__ vlen,
    const unsigned short* __restrict__ h1i,
    const float* __restrict__ bhh0, const float* __restrict__ bih1,
    const float* __restrict__ bhh1,
    float* __restrict__ partial, float* __restrict__ scores,
    unsigned short* __restrict__ ctxb,
    unsigned short* __restrict__ h0A, unsigned short* __restrict__ h0B,
    unsigned short* __restrict__ outsb,
    unsigned* __restrict__ bar) {
  __shared__ unsigned sh1u[512];             // h1old bf16-pairs (P12 q, P5 y)
  __shared__ unsigned sh0u[512];             // h0old (P4 y), staged in P12
  __shared__ unsigned sxu[512];              // x-side (ctx / h0new)
  __shared__ float qs[32];
  __shared__ float aux[640];                 // 128 scores + 512 ctx partials
  __shared__ unsigned short keysl[128 * 32]; // keys[b] 32-col slice (8 KB)
  __shared__ unsigned short encl[128 * 32];  // enc[b]  32-col slice (8 KB)
  const int bid = blockIdx.x, t = threadIdx.x;
  const int b = bid >> 5, sl = bid & 31;
  const int vb = vlen[b];
  unsigned* rel = bar + 16384;
  unsigned ep = 0;

  // ---- one-time: stage this block's keys/enc slices into LDS ----
  for (int i = t; i < 1024; i += 256) {
    int s = i >> 3, q = i & 3;
    if (i & 4) {
      *(u16x4*)(encl + s * 32 + q * 8) =
          *(const u16x4*)(encb + (size_t)(b * SS + s) * HH + sl * 32 + q * 8);
      *(u16x4*)(encl + s * 32 + q * 8 + 4) =
          *(const u16x4*)(encb + (size_t)(b * SS + s) * HH + sl * 32 + q * 8 + 4);
    } else {
      *(u16x4*)(keysl + s * 32 + q * 8) =
          *(const u16x4*)(keysb + (size_t)(b * SS + s) * HH + sl * 32 + q * 8);
      *(u16x4*)(keysl + s * 32 + q * 8 + 4) =
          *(const u16x4*)(keysb + (size_t)(b * SS + s) * HH + sl * 32 + q * 8 + 4);
    }
  }
  __syncthreads();

  // per-b GROUP barrier (32 blocks)
#define GBAR() do { ++ep; __syncthreads();                                     \
    if (t == 0)                                                                \
      __hip_atomic_store(bar + bid * 16, ep, __ATOMIC_RELAXED,                 \
                         __HIP_MEMORY_SCOPE_AGENT);                            \
    if (sl == 0) {                                                             \
      if (t < 32)                                                              \
        while (__hip_atomic_load(bar + (b * 32 + t) * 16, __ATOMIC_RELAXED,    \
                                 __HIP_MEMORY_SCOPE_AGENT) < ep)               \
          __builtin_amdgcn_s_sleep(1);                                         \
      __syncthreads();                                                         \
      if (t == 0)                                                              \
        __hip_atomic_store(rel + b * 16, ep, __ATOMIC_RELAXED,                 \
                           __HIP_MEMORY_SCOPE_AGENT);                          \
    } else if (t == 0) {                                                       \
      while (__hip_atomic_load(rel + b * 16, __ATOMIC_RELAXED,                 \
                               __HIP_MEMORY_SCOPE_AGENT) < ep)                 \
        __builtin_amdgcn_s_sleep(1);                                           \
    }                                                                          \
    __syncthreads(); } while (0)

  for (int td = 0; td < TT; ++td) {
    const unsigned short* h1old =
        td ? outsb + (size_t)(td - 1) * BB * HH : h1i;
    const unsigned short* h0old = (td & 1) ? h0B : h0A;
    unsigned short*       h0new = (td & 1) ? h0A : h0B;

    // ---- P12: stage h1(+h0), q slice (dot2), partial scores (LDS keys) ----
    {
      {
        unsigned long long v1 = ldu64(h1old + b * HH + t * 4);
        unsigned long long v0 = ldu64(h0old + b * HH + t * 4);
        sh1u[t * 2] = (unsigned)v1; sh1u[t * 2 + 1] = (unsigned)(v1 >> 32);
        sh0u[t * 2] = (unsigned)v0; sh0u[t * 2 + 1] = (unsigned)(v0 >> 32);
      }
      __syncthreads();
      {
        const int nl = t >> 3, q8 = t & 7;
        const unsigned short* wr = wqb + (size_t)(sl * 32 + nl) * HH + q8 * 8;
        float acc = 0;
#pragma unroll 4
        for (int j = 0; j < 16; ++j) {
          const int ku = q8 * 4 + j * 32;
          uint4 xv = *(const uint4*)(sh1u + ku);
          dot8(acc, *(const uint4*)(wr + j * 64), xv);
        }
        acc += __shfl_xor(acc, 1); acc += __shfl_xor(acc, 2);
        acc += __shfl_xor(acc, 4);
        if (q8 == 0) qs[nl] = acc;
      }
      __syncthreads();
      const int s = t >> 1, hf = t & 1;
      if (s < vb) {
        const unsigned short* kr = keysl + s * 32 + hf * 16;
        const float* wvp = wv + sl * 32 + hf * 16;
        const float* qp = qs + hf * 16;
        float a = 0;
#pragma unroll
        for (int j = 0; j < 4; ++j) {
          u16x4 kv = *(const u16x4*)(kr + j * 4);
          float4 wvv = *(const float4*)(wvp + j * 4);
          a = fmaf(tanhfast(qp[j * 4 + 0] + bfu(kv[0])), wvv.x, a);
          a = fmaf(tanhfast(qp[j * 4 + 1] + bfu(kv[1])), wvv.y, a);
          a = fmaf(tanhfast(qp[j * 4 + 2] + bfu(kv[2])), wvv.z, a);
          a = fmaf(tanhfast(qp[j * 4 + 3] + bfu(kv[3])), wvv.w, a);
        }
        a += __shfl_xor(a, 1);
        if (hf == 0) stu(partial + ((size_t)(b * SS + s)) * 32 + sl, a);
      }
    }
    GBAR();

    // ---- P3a: block sums its 4 s-rows (32 partials each, 512B coherent) ----
    if (t < 128) {
      const int s = sl * 4 + (t >> 5), g = t & 31;
      float a = 0;
      if (s < vb) {
        a = ldu(partial + ((size_t)(b * SS + s)) * 32 + g);
        a += __shfl_xor(a, 1); a += __shfl_xor(a, 2); a += __shfl_xor(a, 4);
        a += __shfl_xor(a, 8); a += __shfl_xor(a, 16);
      }
      if (g == 0) stu(scores + b * SS + s, (s < vb) ? a : NEGV);
    }
    GBAR();

    // ---- P3b: softmax (512B score reads) -> ctx slice (LDS enc) ----
    {
      if (t < SS) aux[t] = ldu(scores + b * SS + t);
      __syncthreads();
      float mx = aux[0];
      for (int s = 1; s < vb; ++s) mx = fmaxf(mx, aux[s]);
      float p = (t < SS) ? __expf(aux[t] - mx) : 0.f;
      __syncthreads();
      if (t < SS) aux[t] = p;
      __syncthreads();
      float sum = 0;
      for (int s = 0; s < vb; ++s) sum += aux[s];
      const float inv = 1.f / sum;
      const int cp = t & 15, sg = t >> 4;
      float a0 = 0, a1 = 0;
      const int send = min((sg + 1) * 8, vb);
      for (int s = sg * 8; s < send; ++s) {
        unsigned e2 = *(const unsigned*)(encl + s * 32 + cp * 2);
        float pp = aux[s];
        a0 = fmaf(pp, bfu((unsigned short)(e2 & 0xffffu)), a0);
        a1 = fmaf(pp, bfu((unsigned short)(e2 >> 16)), a1);
      }
      aux[SS + sg * 32 + cp * 2]     = a0;
      aux[SS + sg * 32 + cp * 2 + 1] = a1;
      __syncthreads();
      if (t < 32) {
        float v = 0;
#pragma unroll
        for (int g2 = 0; g2 < 16; ++g2) v += aux[SS + g2 * 32 + t];
        stu16(ctxb + b * HH + sl * 32 + t, f2bf(v * inv));
      }
    }
    GBAR();

    // ---- P4: layer-0 gates + GRU -> h0new (y = pre-staged h0old) ----
    gru_phase(sl, t, sxu, sh0u, ctxb + b * HH, wi0, wh0,
              gi0xb + ((size_t)td * BB + b) * H3, nullptr, bhh0,
              h0new + b * HH);
    GBAR();

    // ---- P5: layer-1 gates + GRU -> outsb[td] (y = reused h1old LDS) ----
    gru_phase(sl, t, sxu, sh1u, h0new + b * HH, wi1, wh1,
              nullptr, bih1, bhh1, outsb + (size_t)td * BB * HH + b * HH);
    GBAR();
  }
#undef GBAR
}

// ---------------------------------------------------------------------------
extern "C" void kernel_launch(void* const* d_in, const int* in_sizes, int n_in,
                              void* d_out, int out_size, void* d_ws,
                              size_t ws_size, hipStream_t stream) {
  const int*   X    = (const int*)  d_in[0];
  const float* enc  = (const float*)d_in[1];
  const float* hid  = (const float*)d_in[2];
  const int*   vlen = (const int*)  d_in[3];
  const float* emb  = (const float*)d_in[4];
  const float* Wq   = (const float*)d_in[5];
  const float* Wk   = (const float*)d_in[6];
  const float* wv   = (const float*)d_in[7];
  const float* Wih0 = (const float*)d_in[8];
  const float* Whh0 = (const float*)d_in[9];
  const float* bih0 = (const float*)d_in[10];
  const float* bhh0 = (const float*)d_in[11];
  const float* Wih1 = (const float*)d_in[12];
  const float* Whh1 = (const float*)d_in[13];
  const float* bih1 = (const float*)d_in[14];
  const float* bhh1 = (const float*)d_in[15];
  const float* Wout = (const float*)d_in[16];
  const float* bout = (const float*)d_in[17];
  float* out = (float*)d_out;

  // ---- workspace (float offsets), ~70.6 MB ----
  float* ws = (float*)d_ws;
  unsigned short* wi0b   = (unsigned short*)ws;                 // 4 gate mats
  unsigned short* wh0b   = wi0b + (size_t)3145728;
  unsigned short* wi1b   = wh0b + (size_t)3145728;
  unsigned short* wh1b   = wi1b + (size_t)3145728;
  unsigned short* wqb    = (unsigned short*)(ws + 6291456);
  unsigned short* gi0xb  = (unsigned short*)(ws + 6815744);
  unsigned short* keysb  = (unsigned short*)(ws + 9961472);
  unsigned short* encb   = (unsigned short*)(ws + 12058624);
  unsigned short* xsb    = (unsigned short*)(ws + 14155776);    // prologue only
  unsigned short* wkb    = (unsigned short*)(ws + 14680064);    // prologue only
  unsigned short* wih0xb = (unsigned short*)(ws + 15204352);    // prologue only
  unsigned short* woutb  = (unsigned short*)ws;                 // overlay
  unsigned short* outsb  = (unsigned short*)(ws + 16384000);
  unsigned short* h0A    = (unsigned short*)(ws + 17432576);
  unsigned short* h0B    = (unsigned short*)(ws + 17448960);
  unsigned short* h1i    = (unsigned short*)(ws + 17465344);
  unsigned short* ctxb   = (unsigned short*)(ws + 17481728);
  float*          partial= ws + 17498112;                       // 131,072 f
  float*          scores = ws + 17629184;                       //   4,096 f
  unsigned*       bar    = (unsigned*)(ws + 17633280);          // 16,896 u32

  k_init<<<322, 256, 0, stream>>>(hid, h0A, h1i, bar);
  k_gather<<<1024, 256, 0, stream>>>(X, emb, xsb);
  // bf16 converts for prologue GEMMs
  k_conv<<<4096, 256, 0, stream>>>(enc, encb, 256, HH);
  k_conv<<<1024, 256, 0, stream>>>(Wk, wkb, 256, HH);
  k_conv<<<3072, 256, 0, stream>>>(Wih0 + HH, wih0xb, 128, HH + EE);
  // keysb = bf16(enc @ Wk^T)
  k_gemm_mfma<<<dim3(8, 32), 256, 0, stream>>>(encb, wkb, nullptr,
                                               (float*)keysb, BB * SS, HH, HH,
                                               0, 1);
  // gi0xb = bf16(xs @ W_ih0[:,H:]^T + b_ih0)
  k_gemm_mfma<<<dim3(24, 16), 256, 0, stream>>>(xsb, wih0xb, bih0,
                                                (float*)gi0xb, TT * BB, H3, EE,
                                                0, 1);
  // recurrent weights -> bf16
  k_conv<<<1024, 256, 0, stream>>>(Wq, wqb, 256, HH);
  k_conv<<<3072, 256, 0, stream>>>(Wih0, wi0b, 256, HH + EE);  // ctx cols only
  k_conv<<<3072, 256, 0, stream>>>(Whh0, wh0b, 256, HH);
  k_conv<<<3072, 256, 0, stream>>>(Wih1, wi1b, 256, HH);
  k_conv<<<3072, 256, 0, stream>>>(Whh1, wh1b, 256, HH);

  // the whole 64-step recurrence, one launch, per-b 32-block group barriers
  k_persist<<<NB, 256, 0, stream>>>(keysb, encb, gi0xb, wqb,
                                    wi0b, wh0b, wi1b, wh1b,
                                    wv, vlen, h1i,
                                    bhh0, bih1, bhh1,
                                    partial, scores, ctxb, h0A, h0B, outsb, bar);

  // Wout -> bf16 into the now-dead overlay, then MFMA logits GEMM
  k_conv<<<32000, 256, 0, stream>>>(Wout, woutb, 256, HH);
  k_gemm_mfma<<<dim3(250, 16), 256, 0, stream>>>(outsb, woutb, bout, out,
                                                 TT * BB, VV, HH, 1, 0);
}